// Round 3
// baseline (577.283 us; speedup 1.0000x reference)
//
#include <hip/hip_runtime.h>
#include <stdint.h>

#define TT 2048
#define BB 4
#define HH 768
#define NHEADS 4
#define DD 768
#define NN 3072   // NHEADS*DD
#define LL 3
#define BT 8192   // BB*TT
#define KNB 5

typedef __bf16 bf16x8 __attribute__((ext_vector_type(8)));
typedef float f32x4 __attribute__((ext_vector_type(4)));

__device__ __forceinline__ unsigned short f2bf(float f){
  union { float f; unsigned u; } v; v.f = f;
  unsigned u = v.u;
  return (unsigned short)((u + 0x7FFFu + ((u >> 16) & 1u)) >> 16);
}
__device__ __forceinline__ float bf2f(unsigned short h){
  union { unsigned u; float f; } v; v.u = ((unsigned)h) << 16;
  return v.f;
}

// ---------------- W transpose + bf16 convert: W[l][k][n] fp32 -> Wt[l][n][k] bf16
__global__ void wt_kernel(const float* __restrict__ W, unsigned short* __restrict__ Wt){
  __shared__ float tile[32][33];
  int l = blockIdx.z;
  int n0 = blockIdx.x * 32, k0 = blockIdx.y * 32;
  int tx = threadIdx.x, ty = threadIdx.y; // (32,8)
  const float* Wl = W + (size_t)l * HH * NN;
  for (int r = 0; r < 4; r++)
    tile[ty + r*8][tx] = Wl[(size_t)(k0 + ty + r*8) * NN + n0 + tx];
  __syncthreads();
  unsigned short* Wtl = Wt + (size_t)l * NN * HH;
  for (int r = 0; r < 4; r++){
    int n = n0 + ty + r*8;
    Wtl[(size_t)n * HH + k0 + tx] = f2bf(tile[tx][ty + r*8]);
  }
}

// ---------------- x fp32 -> bf16 (only needed for layer 0; later layers get xb
// from attn_ln epilogue)
__global__ void xconv_kernel(const float* __restrict__ x, unsigned short* __restrict__ xb){
  int i = blockIdx.x * blockDim.x + threadIdx.x; // 4 elems per thread
  float4 v = ((const float4*)x)[i];
  ushort4 o;
  o.x = f2bf(v.x); o.y = f2bf(v.y); o.z = f2bf(v.z); o.w = f2bf(v.w);
  *(ushort4*)(xb + (size_t)i * 4) = o;
}

// ---------------- GEMM: h[BT][NN] bf16 = xb[BT][HH] * Wt^T (Wt is [NN][HH])
// + fused asrc/adst partial dot products (fp32 acc, atomicAdd)
#define BM 128
#define BN 128
#define BK 32
// PAD=34: row stride 17 dwords (odd -> invertible mod 32) => uniform 2-way
// bank aliasing on b128 reads AND writes (2-way is free, m136). PAD=40 gave
// 8 lanes/bank-group => 9.4M conflict cycles/dispatch.
#define PAD 34

__global__ __launch_bounds__(256, 3) void gemm_kernel(
    const unsigned short* __restrict__ xb,
    const unsigned short* __restrict__ wt,
    unsigned short* __restrict__ hout,
    const float* __restrict__ a_srcl,
    const float* __restrict__ a_dstl,
    float* __restrict__ asrc,
    float* __restrict__ adst){
  __shared__ unsigned short xs[BM][PAD];
  __shared__ unsigned short wsd[BN][PAD];
  int bm = blockIdx.y * BM;
  int bn = blockIdx.x * BN;
  int tid = threadIdx.x;
  int wave = tid >> 6, lane = tid & 63;
  int m16 = lane & 15, q = lane >> 4;
  int wm = (wave >> 1) * 64, wn = (wave & 1) * 64;
  int srow = tid >> 2, scol = (tid & 3) * 8;
  const unsigned short* xg  = xb + (size_t)(bm + srow) * HH + scol;
  const unsigned short* xg2 = xb + (size_t)(bm + srow + 64) * HH + scol;
  const unsigned short* wg  = wt + (size_t)(bn + srow) * HH + scol;
  const unsigned short* wg2 = wt + (size_t)(bn + srow + 64) * HH + scol;
  f32x4 acc[4][4] = {};
  // software pipeline: regs hold tile k; loads for k+1 issue right after the
  // first barrier so global latency hides under ds_read + MFMA.
  uint4 xv  = *(const uint4*)(xg);
  uint4 xv2 = *(const uint4*)(xg2);
  uint4 wv  = *(const uint4*)(wg);
  uint4 wv2 = *(const uint4*)(wg2);
  for (int k0 = 0; k0 < HH; k0 += BK){
    *(uint4*)(&xs[srow][scol])       = xv;
    *(uint4*)(&xs[srow + 64][scol])  = xv2;
    *(uint4*)(&wsd[srow][scol])      = wv;
    *(uint4*)(&wsd[srow + 64][scol]) = wv2;
    __syncthreads();
    if (k0 + BK < HH){
      xv  = *(const uint4*)(xg + k0 + BK);
      xv2 = *(const uint4*)(xg2 + k0 + BK);
      wv  = *(const uint4*)(wg + k0 + BK);
      wv2 = *(const uint4*)(wg2 + k0 + BK);
    }
    bf16x8 af[4], bfr[4];
    for (int i = 0; i < 4; i++)
      af[i] = __builtin_bit_cast(bf16x8, *(const uint4*)(&xs[wm + i*16 + m16][q*8]));
    for (int j = 0; j < 4; j++)
      bfr[j] = __builtin_bit_cast(bf16x8, *(const uint4*)(&wsd[wn + j*16 + m16][q*8]));
    for (int i = 0; i < 4; i++)
      for (int j = 0; j < 4; j++)
        acc[i][j] = __builtin_amdgcn_mfma_f32_16x16x32_bf16(af[i], bfr[j], acc[i][j], 0, 0, 0);
    __syncthreads();
  }
  // C store (bf16)
  for (int i = 0; i < 4; i++){
    int row0 = bm + wm + i*16 + q*4;
    for (int j = 0; j < 4; j++){
      int col = bn + wn + j*16 + m16;
      unsigned short* hp = hout + (size_t)row0 * NN + col;
      hp[0]            = f2bf(acc[i][j][0]);
      hp[NN]           = f2bf(acc[i][j][1]);
      hp[2*(size_t)NN] = f2bf(acc[i][j][2]);
      hp[3*(size_t)NN] = f2bf(acc[i][j][3]);
    }
  }
  // fused asrc/adst: per row, sum over this block's 128 cols of h*w.
  // lane holds cols (wn + j*16 + m16); reduce over m16 via 4-step butterfly.
  int head = (bn + wn) / DD;   // 128-col block never straddles a head boundary
  float wsrc[4], wdstw[4];
  for (int j = 0; j < 4; j++){
    int n = bn + wn + j*16 + m16;
    wsrc[j]  = a_srcl[n];
    wdstw[j] = a_dstl[n];
  }
  for (int i = 0; i < 4; i++){
    for (int reg = 0; reg < 4; reg++){
      float ss = 0.f, dd = 0.f;
      for (int j = 0; j < 4; j++){
        float v = acc[i][j][reg];
        ss += v * wsrc[j];
        dd += v * wdstw[j];
      }
      ss += __shfl_xor(ss, 1, 64); dd += __shfl_xor(dd, 1, 64);
      ss += __shfl_xor(ss, 2, 64); dd += __shfl_xor(dd, 2, 64);
      ss += __shfl_xor(ss, 4, 64); dd += __shfl_xor(dd, 4, 64);
      ss += __shfl_xor(ss, 8, 64); dd += __shfl_xor(dd, 8, 64);
      if (m16 == 0){
        int row = bm + wm + i*16 + q*4 + reg;
        atomicAdd(&asrc[row * NHEADS + head], ss);
        atomicAdd(&adst[row * NHEADS + head], dd);
      }
    }
  }
}

// ---------------- attention + head-mean + bias + residual + layernorm
// LDS-staged neighbor rows (coalesced uint4), XCD-swizzled token order,
// emits both fp32 x_out and bf16 xb for the next layer's GEMM.
__global__ __launch_bounds__(256) void attn_ln_kernel(const unsigned short* __restrict__ h,
    const float* __restrict__ asrc, const float* __restrict__ adst,
    const float* __restrict__ x_in, const float* __restrict__ bias_l,
    const float* __restrict__ gamma_l, const float* __restrict__ beta_l,
    float* __restrict__ x_out, unsigned short* __restrict__ xb_next){
  int bid = blockIdx.x;
  // XCD swizzle: round-robin bid%8 -> XCD; give each XCD a contiguous token
  // range so the 5x neighbor-row reuse hits its own L2.
  int token = ((bid & 7) << 10) | (bid >> 3);
  int t = token & (TT - 1);
  int tid = threadIdx.x;
  __shared__ unsigned short hs[KNB][NN];     // 30 KB
  __shared__ float attn_s[NHEADS][KNB];
  __shared__ float rs[4], rq[4];
  // stage 5 neighbor rows, clamped (zero attn weight kills clamped values)
  for (int idx = tid; idx < KNB * (NN/8); idx += 256){
    int k = idx / (NN/8), c = idx % (NN/8);
    int tn = t + k - 2;
    int tnc = min(max(tn, 0), TT - 1);
    const uint4* src = (const uint4*)(h + (size_t)(token + tnc - t) * NN + c*8);
    *(uint4*)(&hs[k][c*8]) = *src;
  }
  if (tid < NHEADS){
    int head = tid;
    float sc[KNB];
    float mx = -3.0e38f;
    float ad = adst[token * NHEADS + head];
    for (int k = 0; k < KNB; k++){
      int tn = t + k - 2;
      if (tn >= 0 && tn < TT){
        float s = asrc[(token + k - 2) * NHEADS + head] + ad;
        s = s > 0.f ? s : 0.2f * s;       // leaky_relu 0.2
        sc[k] = s; mx = fmaxf(mx, s);
      } else sc[k] = -3.0e38f;
    }
    float den = 0.f;
    for (int k = 0; k < KNB; k++){
      float e = (sc[k] > -1.0e38f) ? __expf(sc[k] - mx) : 0.f;
      sc[k] = e; den += e;
    }
    float inv = 0.25f / den;              // fold 1/HEADS into attn
    for (int k = 0; k < KNB; k++) attn_s[head][k] = sc[k] * inv;
  }
  __syncthreads();
  float areg[NHEADS][KNB];
  for (int hd = 0; hd < NHEADS; hd++)
    for (int k = 0; k < KNB; k++) areg[hd][k] = attn_s[hd][k];
  float z[3]; float sum = 0.f, sumsq = 0.f;
  for (int r = 0; r < 3; r++){
    int d = tid + r * 256;
    float y = 0.f;
    for (int k = 0; k < KNB; k++){
      y += areg[0][k] * bf2f(hs[k][d]);
      y += areg[1][k] * bf2f(hs[k][DD + d]);
      y += areg[2][k] * bf2f(hs[k][2*DD + d]);
      y += areg[3][k] * bf2f(hs[k][3*DD + d]);
    }
    float zz = y + bias_l[d] + x_in[(size_t)token * HH + d];
    z[r] = zz; sum += zz; sumsq += zz * zz;
  }
  int wave = tid >> 6, lane = tid & 63;
  for (int off = 32; off > 0; off >>= 1){
    sum += __shfl_xor(sum, off, 64);
    sumsq += __shfl_xor(sumsq, off, 64);
  }
  if (lane == 0){ rs[wave] = sum; rq[wave] = sumsq; }
  __syncthreads();
  float ts = rs[0] + rs[1] + rs[2] + rs[3];
  float tq = rq[0] + rq[1] + rq[2] + rq[3];
  float mean = ts * (1.f / HH);
  float var = tq * (1.f / HH) - mean * mean;
  float rstd = rsqrtf(var + 1e-5f);
  for (int r = 0; r < 3; r++){
    int d = tid + r * 256;
    float o = (z[r] - mean) * rstd * gamma_l[d] + beta_l[d];
    x_out[(size_t)token * HH + d] = o;
    xb_next[(size_t)token * HH + d] = f2bf(o);
  }
}

extern "C" void kernel_launch(void* const* d_in, const int* in_sizes, int n_in,
                              void* d_out, int out_size, void* d_ws, size_t ws_size,
                              hipStream_t stream) {
  const float* x     = (const float*)d_in[0];
  const float* W     = (const float*)d_in[1];
  const float* a_src = (const float*)d_in[2];
  const float* a_dst = (const float*)d_in[3];
  const float* bias  = (const float*)d_in[4];
  const float* gamma = (const float*)d_in[5];
  const float* beta  = (const float*)d_in[6];
  float* out = (float*)d_out;

  char* ws = (char*)d_ws;
  size_t off = 0;
  auto alloc = [&](size_t bytes)->char*{
    char* p = ws + off;
    off = (off + bytes + 255) & ~(size_t)255;
    return p;
  };
  unsigned short* wt   = (unsigned short*)alloc((size_t)LL * NN * HH * 2);
  unsigned short* xb   = (unsigned short*)alloc((size_t)BT * HH * 2);
  unsigned short* hbuf = (unsigned short*)alloc((size_t)BT * NN * 2);
  float* asrcb = (float*)alloc((size_t)BT * NHEADS * 4);
  float* adstb = (float*)alloc((size_t)BT * NHEADS * 4);

  wt_kernel<<<dim3(NN/32, HH/32, LL), dim3(32, 8), 0, stream>>>(W, wt);
  xconv_kernel<<<(BT * HH / 4) / 256, 256, 0, stream>>>(x, xb);

  for (int l = 0; l < LL; l++){
    const float* xin = (l == 0) ? x : out;
    hipMemsetAsync(asrcb, 0, (size_t)BT * NHEADS * 4, stream);
    hipMemsetAsync(adstb, 0, (size_t)BT * NHEADS * 4, stream);
    gemm_kernel<<<dim3(NN / BN, BT / BM), 256, 0, stream>>>(
        xb, wt + (size_t)l * NN * HH, hbuf,
        a_src + (size_t)l * NHEADS * DD, a_dst + (size_t)l * NHEADS * DD,
        asrcb, adstb);
    attn_ln_kernel<<<BT, 256, 0, stream>>>(hbuf, asrcb, adstb, xin,
        bias + (size_t)l * DD, gamma + (size_t)l * HH, beta + (size_t)l * HH,
        out, xb);
  }
}

// Round 4
// 422.049 us; speedup vs baseline: 1.3678x; 1.3678x over previous
//
#include <hip/hip_runtime.h>
#include <stdint.h>

#define TT 2048
#define BB 4
#define HH 768
#define NHEADS 4
#define DD 768
#define NN 3072   // NHEADS*DD
#define LL 3
#define BT 8192   // BB*TT
#define KNB 5
#define NBLK 12   // 64-col partial blocks per head (DD/64)

typedef __bf16 bf16x8 __attribute__((ext_vector_type(8)));
typedef float f32x4 __attribute__((ext_vector_type(4)));

__device__ __forceinline__ unsigned short f2bf(float f){
  union { float f; unsigned u; } v; v.f = f;
  unsigned u = v.u;
  return (unsigned short)((u + 0x7FFFu + ((u >> 16) & 1u)) >> 16);
}
__device__ __forceinline__ float bf2f(unsigned short h){
  union { unsigned u; float f; } v; v.u = ((unsigned)h) << 16;
  return v.f;
}

// ---------------- W transpose + bf16 convert: W[l][k][n] fp32 -> Wt[l][n][k] bf16
__global__ void wt_kernel(const float* __restrict__ W, unsigned short* __restrict__ Wt){
  __shared__ float tile[32][33];
  int l = blockIdx.z;
  int n0 = blockIdx.x * 32, k0 = blockIdx.y * 32;
  int tx = threadIdx.x, ty = threadIdx.y; // (32,8)
  const float* Wl = W + (size_t)l * HH * NN;
  for (int r = 0; r < 4; r++)
    tile[ty + r*8][tx] = Wl[(size_t)(k0 + ty + r*8) * NN + n0 + tx];
  __syncthreads();
  unsigned short* Wtl = Wt + (size_t)l * NN * HH;
  for (int r = 0; r < 4; r++){
    int n = n0 + ty + r*8;
    Wtl[(size_t)n * HH + k0 + tx] = f2bf(tile[tx][ty + r*8]);
  }
}

// ---------------- x fp32 -> bf16 (layer 0 only; attn_ln emits xb afterwards)
__global__ void xconv_kernel(const float* __restrict__ x, unsigned short* __restrict__ xb){
  int i = blockIdx.x * blockDim.x + threadIdx.x;
  float4 v = ((const float4*)x)[i];
  ushort4 o;
  o.x = f2bf(v.x); o.y = f2bf(v.y); o.z = f2bf(v.z); o.w = f2bf(v.w);
  *(ushort4*)(xb + (size_t)i * 4) = o;
}

// ---------------- GEMM: h[BT][NN] bf16 = xb[BT][HH] * Wt^T (Wt is [NN][HH])
// R2 known-good K-loop (66 us): PAD=40, no software pipeline, lb(256,2).
// Fused asrc/adst partials stored NON-atomically (R3's atomics cost +24MB HBM
// writes + contention).
#define BM 128
#define BN 128
#define BK 32
#define PAD 40

__global__ __launch_bounds__(256, 2) void gemm_kernel(
    const unsigned short* __restrict__ xb,
    const unsigned short* __restrict__ wt,
    unsigned short* __restrict__ hout,
    const float* __restrict__ a_srcl,
    const float* __restrict__ a_dstl,
    float* __restrict__ psrc,     // [BT][NHEADS][NBLK]
    float* __restrict__ pdst){
  __shared__ unsigned short xs[BM][PAD];
  __shared__ unsigned short wsd[BN][PAD];
  int bm = blockIdx.y * BM;
  int bn = blockIdx.x * BN;
  int tid = threadIdx.x;
  int wave = tid >> 6, lane = tid & 63;
  int m16 = lane & 15, q = lane >> 4;
  int wm = (wave >> 1) * 64, wn = (wave & 1) * 64;
  int srow = tid >> 2, scol = (tid & 3) * 8;
  const unsigned short* xg  = xb + (size_t)(bm + srow) * HH + scol;
  const unsigned short* xg2 = xb + (size_t)(bm + srow + 64) * HH + scol;
  const unsigned short* wg  = wt + (size_t)(bn + srow) * HH + scol;
  const unsigned short* wg2 = wt + (size_t)(bn + srow + 64) * HH + scol;
  f32x4 acc[4][4] = {};
  for (int k0 = 0; k0 < HH; k0 += BK){
    uint4 xv  = *(const uint4*)(xg + k0);
    uint4 xv2 = *(const uint4*)(xg2 + k0);
    uint4 wv  = *(const uint4*)(wg + k0);
    uint4 wv2 = *(const uint4*)(wg2 + k0);
    *(uint4*)(&xs[srow][scol])       = xv;
    *(uint4*)(&xs[srow + 64][scol])  = xv2;
    *(uint4*)(&wsd[srow][scol])      = wv;
    *(uint4*)(&wsd[srow + 64][scol]) = wv2;
    __syncthreads();
    bf16x8 af[4], bfr[4];
    for (int i = 0; i < 4; i++)
      af[i] = __builtin_bit_cast(bf16x8, *(const uint4*)(&xs[wm + i*16 + m16][q*8]));
    for (int j = 0; j < 4; j++)
      bfr[j] = __builtin_bit_cast(bf16x8, *(const uint4*)(&wsd[wn + j*16 + m16][q*8]));
    for (int i = 0; i < 4; i++)
      for (int j = 0; j < 4; j++)
        acc[i][j] = __builtin_amdgcn_mfma_f32_16x16x32_bf16(af[i], bfr[j], acc[i][j], 0, 0, 0);
    __syncthreads();
  }
  // C store (bf16)
  for (int i = 0; i < 4; i++){
    int row0 = bm + wm + i*16 + q*4;
    for (int j = 0; j < 4; j++){
      int col = bn + wn + j*16 + m16;
      unsigned short* hp = hout + (size_t)row0 * NN + col;
      hp[0]            = f2bf(acc[i][j][0]);
      hp[NN]           = f2bf(acc[i][j][1]);
      hp[2*(size_t)NN] = f2bf(acc[i][j][2]);
      hp[3*(size_t)NN] = f2bf(acc[i][j][3]);
    }
  }
  // fused asrc/adst partials: this wave covers 64 cols (one head, one NBLK slot)
  int col0 = bn + wn;
  int head = col0 / DD;
  int blk  = (col0 % DD) >> 6;   // 0..11
  float wsrc[4], wdstw[4];
  for (int j = 0; j < 4; j++){
    int n = col0 + j*16 + m16;
    wsrc[j]  = a_srcl[n];
    wdstw[j] = a_dstl[n];
  }
  for (int i = 0; i < 4; i++){
    for (int reg = 0; reg < 4; reg++){
      float ss = 0.f, dd = 0.f;
      for (int j = 0; j < 4; j++){
        float v = acc[i][j][reg];
        ss += v * wsrc[j];
        dd += v * wdstw[j];
      }
      ss += __shfl_xor(ss, 1, 64); dd += __shfl_xor(dd, 1, 64);
      ss += __shfl_xor(ss, 2, 64); dd += __shfl_xor(dd, 2, 64);
      ss += __shfl_xor(ss, 4, 64); dd += __shfl_xor(dd, 4, 64);
      ss += __shfl_xor(ss, 8, 64); dd += __shfl_xor(dd, 8, 64);
      if (m16 == 0){
        int row = bm + wm + i*16 + q*4 + reg;
        size_t slot = (size_t)row * (NHEADS * NBLK) + head * NBLK + blk;
        psrc[slot] = ss;
        pdst[slot] = dd;
      }
    }
  }
}

// ---------------- reduce partials -> asrc/adst
__global__ __launch_bounds__(256) void srcred_kernel(
    const float* __restrict__ psrc, const float* __restrict__ pdst,
    float* __restrict__ asrc, float* __restrict__ adst){
  int task = blockIdx.x * 256 + threadIdx.x;   // row*NHEADS + head
  const float* ps = psrc + (size_t)task * NBLK;
  const float* pd = pdst + (size_t)task * NBLK;
  float ss = 0.f, dd = 0.f;
  for (int i = 0; i < NBLK; i++){ ss += ps[i]; dd += pd[i]; }
  asrc[task] = ss;
  adst[task] = dd;
}

// ---------------- attention + head-mean + bias + residual + layernorm
__global__ __launch_bounds__(256) void attn_ln_kernel(const unsigned short* __restrict__ h,
    const float* __restrict__ asrc, const float* __restrict__ adst,
    const float* __restrict__ x_in, const float* __restrict__ bias_l,
    const float* __restrict__ gamma_l, const float* __restrict__ beta_l,
    float* __restrict__ x_out, unsigned short* __restrict__ xb_next){
  int bid = blockIdx.x;
  int token = ((bid & 7) << 10) | (bid >> 3);  // XCD-contiguous token ranges
  int t = token & (TT - 1);
  int tid = threadIdx.x;
  __shared__ unsigned short hs[KNB][NN];     // 30 KB
  __shared__ float attn_s[NHEADS][KNB];
  __shared__ float rs[4], rq[4];
  for (int idx = tid; idx < KNB * (NN/8); idx += 256){
    int k = idx / (NN/8), c = idx % (NN/8);
    int tn = t + k - 2;
    int tnc = min(max(tn, 0), TT - 1);
    const uint4* src = (const uint4*)(h + (size_t)(token + tnc - t) * NN + c*8);
    *(uint4*)(&hs[k][c*8]) = *src;
  }
  if (tid < NHEADS){
    int head = tid;
    float sc[KNB];
    float mx = -3.0e38f;
    float ad = adst[token * NHEADS + head];
    for (int k = 0; k < KNB; k++){
      int tn = t + k - 2;
      if (tn >= 0 && tn < TT){
        float s = asrc[(token + k - 2) * NHEADS + head] + ad;
        s = s > 0.f ? s : 0.2f * s;       // leaky_relu 0.2
        sc[k] = s; mx = fmaxf(mx, s);
      } else sc[k] = -3.0e38f;
    }
    float den = 0.f;
    for (int k = 0; k < KNB; k++){
      float e = (sc[k] > -1.0e38f) ? __expf(sc[k] - mx) : 0.f;
      sc[k] = e; den += e;
    }
    float inv = 0.25f / den;              // fold 1/HEADS into attn
    for (int k = 0; k < KNB; k++) attn_s[head][k] = sc[k] * inv;
  }
  __syncthreads();
  float areg[NHEADS][KNB];
  for (int hd = 0; hd < NHEADS; hd++)
    for (int k = 0; k < KNB; k++) areg[hd][k] = attn_s[hd][k];
  float z[3]; float sum = 0.f, sumsq = 0.f;
  for (int r = 0; r < 3; r++){
    int d = tid + r * 256;
    float y = 0.f;
    for (int k = 0; k < KNB; k++){
      y += areg[0][k] * bf2f(hs[k][d]);
      y += areg[1][k] * bf2f(hs[k][DD + d]);
      y += areg[2][k] * bf2f(hs[k][2*DD + d]);
      y += areg[3][k] * bf2f(hs[k][3*DD + d]);
    }
    float zz = y + bias_l[d] + x_in[(size_t)token * HH + d];
    z[r] = zz; sum += zz; sumsq += zz * zz;
  }
  int wave = tid >> 6, lane = tid & 63;
  for (int off = 32; off > 0; off >>= 1){
    sum += __shfl_xor(sum, off, 64);
    sumsq += __shfl_xor(sumsq, off, 64);
  }
  if (lane == 0){ rs[wave] = sum; rq[wave] = sumsq; }
  __syncthreads();
  float ts = rs[0] + rs[1] + rs[2] + rs[3];
  float tq = rq[0] + rq[1] + rq[2] + rq[3];
  float mean = ts * (1.f / HH);
  float var = tq * (1.f / HH) - mean * mean;
  float rstd = rsqrtf(var + 1e-5f);
  for (int r = 0; r < 3; r++){
    int d = tid + r * 256;
    float o = (z[r] - mean) * rstd * gamma_l[d] + beta_l[d];
    x_out[(size_t)token * HH + d] = o;
    xb_next[(size_t)token * HH + d] = f2bf(o);
  }
}

extern "C" void kernel_launch(void* const* d_in, const int* in_sizes, int n_in,
                              void* d_out, int out_size, void* d_ws, size_t ws_size,
                              hipStream_t stream) {
  const float* x     = (const float*)d_in[0];
  const float* W     = (const float*)d_in[1];
  const float* a_src = (const float*)d_in[2];
  const float* a_dst = (const float*)d_in[3];
  const float* bias  = (const float*)d_in[4];
  const float* gamma = (const float*)d_in[5];
  const float* beta  = (const float*)d_in[6];
  float* out = (float*)d_out;

  char* ws = (char*)d_ws;
  size_t off = 0;
  auto alloc = [&](size_t bytes)->char*{
    char* p = ws + off;
    off = (off + bytes + 255) & ~(size_t)255;
    return p;
  };
  unsigned short* wt   = (unsigned short*)alloc((size_t)LL * NN * HH * 2);
  unsigned short* xb   = (unsigned short*)alloc((size_t)BT * HH * 2);
  unsigned short* hbuf = (unsigned short*)alloc((size_t)BT * NN * 2);
  float* psrc  = (float*)alloc((size_t)BT * NHEADS * NBLK * 4);
  float* pdst  = (float*)alloc((size_t)BT * NHEADS * NBLK * 4);
  float* asrcb = (float*)alloc((size_t)BT * NHEADS * 4);
  float* adstb = (float*)alloc((size_t)BT * NHEADS * 4);

  wt_kernel<<<dim3(NN/32, HH/32, LL), dim3(32, 8), 0, stream>>>(W, wt);
  xconv_kernel<<<(BT * HH / 4) / 256, 256, 0, stream>>>(x, xb);

  for (int l = 0; l < LL; l++){
    const float* xin = (l == 0) ? x : out;
    gemm_kernel<<<dim3(NN / BN, BT / BM), 256, 0, stream>>>(
        xb, wt + (size_t)l * NN * HH, hbuf,
        a_src + (size_t)l * NHEADS * DD, a_dst + (size_t)l * NHEADS * DD,
        psrc, pdst);
    srcred_kernel<<<BT * NHEADS / 256, 256, 0, stream>>>(psrc, pdst, asrcb, adstb);
    attn_ln_kernel<<<BT, 256, 0, stream>>>(hbuf, asrcb, adstb, xin,
        bias + (size_t)l * DD, gamma + (size_t)l * HH, beta + (size_t)l * HH,
        out, xb);
  }
}

// Round 5
// 373.987 us; speedup vs baseline: 1.5436x; 1.1285x over previous
//
#include <hip/hip_runtime.h>
#include <stdint.h>

#define TT 2048
#define BB 4
#define HH 768
#define NHEADS 4
#define DD 768
#define NN 3072   // NHEADS*DD
#define LL 3
#define BT 8192   // BB*TT
#define KNB 5
#define NBLK 12   // 64-col partial blocks per head (DD/64)
#define TPB 4     // tokens per attn block
#define NROWS 8   // TPB + KNB - 1

typedef __bf16 bf16x8 __attribute__((ext_vector_type(8)));
typedef float f32x4 __attribute__((ext_vector_type(4)));

__device__ __forceinline__ unsigned short f2bf(float f){
  union { float f; unsigned u; } v; v.f = f;
  unsigned u = v.u;
  return (unsigned short)((u + 0x7FFFu + ((u >> 16) & 1u)) >> 16);
}
__device__ __forceinline__ float bf2f(unsigned short h){
  union { unsigned u; float f; } v; v.u = ((unsigned)h) << 16;
  return v.f;
}
// async global->LDS, 16B per lane; LDS dest = wave-uniform base + lane*16
__device__ __forceinline__ void gload16(const unsigned short* g, unsigned short* l){
  __builtin_amdgcn_global_load_lds((const __attribute__((address_space(1))) void*)g,
                                   (__attribute__((address_space(3))) void*)l, 16, 0, 0);
}

// ---------------- W transpose + bf16 convert: W[l][k][n] fp32 -> Wt[l][n][k] bf16
__global__ void wt_kernel(const float* __restrict__ W, unsigned short* __restrict__ Wt){
  __shared__ float tile[32][33];
  int l = blockIdx.z;
  int n0 = blockIdx.x * 32, k0 = blockIdx.y * 32;
  int tx = threadIdx.x, ty = threadIdx.y; // (32,8)
  const float* Wl = W + (size_t)l * HH * NN;
  for (int r = 0; r < 4; r++)
    tile[ty + r*8][tx] = Wl[(size_t)(k0 + ty + r*8) * NN + n0 + tx];
  __syncthreads();
  unsigned short* Wtl = Wt + (size_t)l * NN * HH;
  for (int r = 0; r < 4; r++){
    int n = n0 + ty + r*8;
    Wtl[(size_t)n * HH + k0 + tx] = f2bf(tile[tx][ty + r*8]);
  }
}

// ---------------- x fp32 -> bf16 (layer 0 only; attn_ln emits xb afterwards)
__global__ void xconv_kernel(const float* __restrict__ x, unsigned short* __restrict__ xb){
  int i = blockIdx.x * blockDim.x + threadIdx.x;
  float4 v = ((const float4*)x)[i];
  ushort4 o;
  o.x = f2bf(v.x); o.y = f2bf(v.y); o.z = f2bf(v.z); o.w = f2bf(v.w);
  *(ushort4*)(xb + (size_t)i * 4) = o;
}

// ---------------- GEMM: h[BT][NN] bf16 = xb[BT][HH] * Wt^T (Wt is [NN][HH])
// m97-style staging: global_load_lds width=16, unpadded LDS tiles with XOR
// chunk swizzle (chunk c of row r lives at position c ^ ((r>>1)&3)) so the
// b128 fragment reads are uniform 2-way (free) instead of 8-way.
#define BM 128
#define BN 128
#define BK 32

__global__ __launch_bounds__(256, 2) void gemm_kernel(
    const unsigned short* __restrict__ xb,
    const unsigned short* __restrict__ wt,
    unsigned short* __restrict__ hout,
    const float* __restrict__ a_srcl,
    const float* __restrict__ a_dstl,
    float* __restrict__ psrc,     // [BT][NHEADS][NBLK]
    float* __restrict__ pdst){
  __shared__ __align__(16) unsigned short xs[BM][32];
  __shared__ __align__(16) unsigned short wsd[BN][32];
  int bm = blockIdx.y * BM;
  int bn = blockIdx.x * BN;
  int tid = threadIdx.x;
  int wave = tid >> 6, lane = tid & 63;
  int m16 = lane & 15, q = lane >> 4;
  int wm = (wave >> 1) * 64, wn = (wave & 1) * 64;
  // staging: wave w stages rows [w*32, w*32+32) of both tiles (2 segments of
  // 16 rows x 64B = 1KB each). lane -> row seg+lane>>2, fetched chunk is
  // swizzled: c = (lane&3) ^ ((row>>1)&3) = (lane&3) ^ ((lane>>3)&3).
  int rA = wave * 32 + (lane >> 2);
  int cc = (lane & 3) ^ ((lane >> 3) & 3);
  const unsigned short* ga0 = xb + (size_t)(bm + rA) * HH + cc * 8;
  const unsigned short* ga1 = ga0 + (size_t)16 * HH;
  const unsigned short* gb0 = wt + (size_t)(bn + rA) * HH + cc * 8;
  const unsigned short* gb1 = gb0 + (size_t)16 * HH;
  unsigned short* la0 = &xs[wave * 32][0];
  unsigned short* la1 = &xs[wave * 32 + 16][0];
  unsigned short* lb0 = &wsd[wave * 32][0];
  unsigned short* lb1 = &wsd[wave * 32 + 16][0];
  int sw = (m16 >> 1) & 3;         // read-side swizzle (row>>1)&3 == (m16>>1)&3
  int rdcol = (q ^ sw) * 8;
  f32x4 acc[4][4] = {};
  for (int k0 = 0; k0 < HH; k0 += BK){
    gload16(ga0 + k0, la0);
    gload16(ga1 + k0, la1);
    gload16(gb0 + k0, lb0);
    gload16(gb1 + k0, lb1);
    __syncthreads();
    bf16x8 af[4], bfr[4];
    for (int i = 0; i < 4; i++)
      af[i] = __builtin_bit_cast(bf16x8, *(const uint4*)(&xs[wm + i*16 + m16][rdcol]));
    for (int j = 0; j < 4; j++)
      bfr[j] = __builtin_bit_cast(bf16x8, *(const uint4*)(&wsd[wn + j*16 + m16][rdcol]));
    for (int i = 0; i < 4; i++)
      for (int j = 0; j < 4; j++)
        acc[i][j] = __builtin_amdgcn_mfma_f32_16x16x32_bf16(af[i], bfr[j], acc[i][j], 0, 0, 0);
    __syncthreads();
  }
  // C store (bf16)
  for (int i = 0; i < 4; i++){
    int row0 = bm + wm + i*16 + q*4;
    for (int j = 0; j < 4; j++){
      int col = bn + wn + j*16 + m16;
      unsigned short* hp = hout + (size_t)row0 * NN + col;
      hp[0]            = f2bf(acc[i][j][0]);
      hp[NN]           = f2bf(acc[i][j][1]);
      hp[2*(size_t)NN] = f2bf(acc[i][j][2]);
      hp[3*(size_t)NN] = f2bf(acc[i][j][3]);
    }
  }
  // fused asrc/adst partials: wave covers 64 cols = one (head, blk) slot
  int col0 = bn + wn;
  int head = col0 / DD;
  int blk  = (col0 % DD) >> 6;
  float wsrc[4], wdstw[4];
  for (int j = 0; j < 4; j++){
    int n = col0 + j*16 + m16;
    wsrc[j]  = a_srcl[n];
    wdstw[j] = a_dstl[n];
  }
  for (int i = 0; i < 4; i++){
    for (int reg = 0; reg < 4; reg++){
      float ss = 0.f, dd = 0.f;
      for (int j = 0; j < 4; j++){
        float v = acc[i][j][reg];
        ss += v * wsrc[j];
        dd += v * wdstw[j];
      }
      ss += __shfl_xor(ss, 1, 64); dd += __shfl_xor(dd, 1, 64);
      ss += __shfl_xor(ss, 2, 64); dd += __shfl_xor(dd, 2, 64);
      ss += __shfl_xor(ss, 4, 64); dd += __shfl_xor(dd, 4, 64);
      ss += __shfl_xor(ss, 8, 64); dd += __shfl_xor(dd, 8, 64);
      if (m16 == 0){
        int row = bm + wm + i*16 + q*4 + reg;
        size_t slot = (size_t)row * (NHEADS * NBLK) + head * NBLK + blk;
        psrc[slot] = ss;
        pdst[slot] = dd;
      }
    }
  }
}

// ---------------- reduce partials -> asrc/adst
__global__ __launch_bounds__(256) void srcred_kernel(
    const float* __restrict__ psrc, const float* __restrict__ pdst,
    float* __restrict__ asrc, float* __restrict__ adst){
  int task = blockIdx.x * 256 + threadIdx.x;   // row*NHEADS + head
  const float* ps = psrc + (size_t)task * NBLK;
  const float* pd = pdst + (size_t)task * NBLK;
  float ss = 0.f, dd = 0.f;
  for (int i = 0; i < NBLK; i++){ ss += ps[i]; dd += pd[i]; }
  asrc[task] = ss;
  adst[task] = dd;
}

// ---------------- attention + head-mean + bias + residual + layernorm
// 4 tokens/block: 8 staged rows serve all 4 windows (2.5x less staging);
// hs loads hoisted across tokens (each v feeds up to 4 tokens' FMAs).
__global__ __launch_bounds__(256) void attn_ln_kernel(const unsigned short* __restrict__ h,
    const float* __restrict__ asrc, const float* __restrict__ adst,
    const float* __restrict__ x_in, const float* __restrict__ bias_l,
    const float* __restrict__ gamma_l, const float* __restrict__ beta_l,
    float* __restrict__ x_out, unsigned short* __restrict__ xb_next){
  int bid = blockIdx.x;                       // 2048
  int grp = ((bid & 7) << 8) | (bid >> 3);    // XCD-contiguous groups
  int token0 = grp * TPB;
  int t0 = token0 & (TT - 1);
  int bseq = token0 >> 11;                    // token0 / TT
  int tid = threadIdx.x;
  int wave = tid >> 6, lane = tid & 63;
  __shared__ __align__(16) unsigned short hs[NROWS][NN];   // 48 KB
  __shared__ float attn_s[TPB][NHEADS][KNB];
  __shared__ float rs[4][TPB], rq[4][TPB];
  // stage 8 rows (clamped) via global_load_lds: 3072 uint4 = 12 iters
  for (int it = 0; it < 12; it++){
    int idx = it * 256 + tid;
    int j = idx / (NN/8);
    int c = idx % (NN/8);
    int g = t0 - 2 + j;
    g = min(max(g, 0), TT - 1);
    const unsigned short* src = h + ((size_t)(bseq * TT + g)) * NN + c * 8;
    gload16(src, ((unsigned short*)hs) + (size_t)(it * 256 + wave * 64) * 8);
  }
  if (tid < TPB * NHEADS){
    int ti = tid >> 2, head = tid & 3;
    int token = token0 + ti, t = t0 + ti;
    float sc[KNB];
    float mx = -3.0e38f;
    float ad = adst[token * NHEADS + head];
    for (int k = 0; k < KNB; k++){
      int tn = t + k - 2;
      if (tn >= 0 && tn < TT){
        float s = asrc[(token + k - 2) * NHEADS + head] + ad;
        s = s > 0.f ? s : 0.2f * s;       // leaky_relu 0.2
        sc[k] = s; mx = fmaxf(mx, s);
      } else sc[k] = -3.0e38f;
    }
    float den = 0.f;
    for (int k = 0; k < KNB; k++){
      float e = (sc[k] > -1.0e38f) ? __expf(sc[k] - mx) : 0.f;
      sc[k] = e; den += e;
    }
    float inv = 0.25f / den;              // fold 1/HEADS into attn
    for (int k = 0; k < KNB; k++) attn_s[ti][head][k] = sc[k] * inv;
  }
  __syncthreads();
  float y[3][TPB] = {};
  for (int hd = 0; hd < NHEADS; hd++){
    float ac[TPB][KNB];
    for (int ti = 0; ti < TPB; ti++)
      for (int k = 0; k < KNB; k++) ac[ti][k] = attn_s[ti][hd][k];
    for (int r = 0; r < 3; r++){
      int d = hd * DD + tid + r * 256;
      for (int j = 0; j < NROWS; j++){
        float v = bf2f(hs[j][d]);
        #pragma unroll
        for (int ti = 0; ti < TPB; ti++){
          int k = j - ti;
          if (k >= 0 && k < KNB) y[r][ti] += ac[ti][k] * v;
        }
      }
    }
  }
  float sum[TPB] = {}, sq[TPB] = {};
  for (int r = 0; r < 3; r++){
    int d = tid + r * 256;
    float bl = bias_l[d];
    for (int ti = 0; ti < TPB; ti++){
      float zz = y[r][ti] + bl + x_in[(size_t)(token0 + ti) * HH + d];
      y[r][ti] = zz; sum[ti] += zz; sq[ti] += zz * zz;
    }
  }
  for (int off = 32; off > 0; off >>= 1){
    for (int ti = 0; ti < TPB; ti++){
      sum[ti] += __shfl_xor(sum[ti], off, 64);
      sq[ti]  += __shfl_xor(sq[ti], off, 64);
    }
  }
  if (lane == 0)
    for (int ti = 0; ti < TPB; ti++){ rs[wave][ti] = sum[ti]; rq[wave][ti] = sq[ti]; }
  __syncthreads();
  for (int ti = 0; ti < TPB; ti++){
    float ts = rs[0][ti] + rs[1][ti] + rs[2][ti] + rs[3][ti];
    float tq = rq[0][ti] + rq[1][ti] + rq[2][ti] + rq[3][ti];
    float mean = ts * (1.f / HH);
    float var = tq * (1.f / HH) - mean * mean;
    float rstd = rsqrtf(var + 1e-5f);
    for (int r = 0; r < 3; r++){
      int d = tid + r * 256;
      float o = (y[r][ti] - mean) * rstd * gamma_l[d] + beta_l[d];
      x_out[(size_t)(token0 + ti) * HH + d] = o;
      xb_next[(size_t)(token0 + ti) * HH + d] = f2bf(o);
    }
  }
}

extern "C" void kernel_launch(void* const* d_in, const int* in_sizes, int n_in,
                              void* d_out, int out_size, void* d_ws, size_t ws_size,
                              hipStream_t stream) {
  const float* x     = (const float*)d_in[0];
  const float* W     = (const float*)d_in[1];
  const float* a_src = (const float*)d_in[2];
  const float* a_dst = (const float*)d_in[3];
  const float* bias  = (const float*)d_in[4];
  const float* gamma = (const float*)d_in[5];
  const float* beta  = (const float*)d_in[6];
  float* out = (float*)d_out;

  char* ws = (char*)d_ws;
  size_t off = 0;
  auto alloc = [&](size_t bytes)->char*{
    char* p = ws + off;
    off = (off + bytes + 255) & ~(size_t)255;
    return p;
  };
  unsigned short* wt   = (unsigned short*)alloc((size_t)LL * NN * HH * 2);
  unsigned short* xb   = (unsigned short*)alloc((size_t)BT * HH * 2);
  unsigned short* hbuf = (unsigned short*)alloc((size_t)BT * NN * 2);
  float* psrc  = (float*)alloc((size_t)BT * NHEADS * NBLK * 4);
  float* pdst  = (float*)alloc((size_t)BT * NHEADS * NBLK * 4);
  float* asrcb = (float*)alloc((size_t)BT * NHEADS * 4);
  float* adstb = (float*)alloc((size_t)BT * NHEADS * 4);

  wt_kernel<<<dim3(NN/32, HH/32, LL), dim3(32, 8), 0, stream>>>(W, wt);
  xconv_kernel<<<(BT * HH / 4) / 256, 256, 0, stream>>>(x, xb);

  for (int l = 0; l < LL; l++){
    const float* xin = (l == 0) ? x : out;
    gemm_kernel<<<dim3(NN / BN, BT / BM), 256, 0, stream>>>(
        xb, wt + (size_t)l * NN * HH, hbuf,
        a_src + (size_t)l * NHEADS * DD, a_dst + (size_t)l * NHEADS * DD,
        psrc, pdst);
    srcred_kernel<<<BT * NHEADS / 256, 256, 0, stream>>>(psrc, pdst, asrcb, adstb);
    attn_ln_kernel<<<BT / TPB, 256, 0, stream>>>(hbuf, asrcb, adstb, xin,
        bias + (size_t)l * DD, gamma + (size_t)l * HH, beta + (size_t)l * HH,
        out, xb);
  }
}

// Round 6
// 340.070 us; speedup vs baseline: 1.6975x; 1.0997x over previous
//
#include <hip/hip_runtime.h>
#include <stdint.h>

#define TT 2048
#define BB 4
#define HH 768
#define NHEADS 4
#define DD 768
#define NN 3072   // NHEADS*DD
#define LL 3
#define BT 8192   // BB*TT
#define KNB 5
#define NBLK 12   // 64-col partial blocks per head (DD/64)
#define ATPB 4    // tokens per attn block
#define NROWS 8   // ATPB + KNB - 1

typedef __bf16 bf16x8 __attribute__((ext_vector_type(8)));
typedef float f32x4 __attribute__((ext_vector_type(4)));

__device__ __forceinline__ unsigned short f2bf(float f){
  union { float f; unsigned u; } v; v.f = f;
  unsigned u = v.u;
  return (unsigned short)((u + 0x7FFFu + ((u >> 16) & 1u)) >> 16);
}
__device__ __forceinline__ float bf2f(unsigned short h){
  union { unsigned u; float f; } v; v.u = ((unsigned)h) << 16;
  return v.f;
}
// async global->LDS, 16B per lane; LDS dest = wave-uniform base + lane*16
__device__ __forceinline__ void gload16(const unsigned short* g, unsigned short* l){
  __builtin_amdgcn_global_load_lds((const __attribute__((address_space(1))) void*)g,
                                   (__attribute__((address_space(3))) void*)l, 16, 0, 0);
}

// ---------------- W transpose + bf16 convert: W[l][k][n] fp32 -> Wt[l][n][k] bf16
__global__ void wt_kernel(const float* __restrict__ W, unsigned short* __restrict__ Wt){
  __shared__ float tile[32][33];
  int l = blockIdx.z;
  int n0 = blockIdx.x * 32, k0 = blockIdx.y * 32;
  int tx = threadIdx.x, ty = threadIdx.y; // (32,8)
  const float* Wl = W + (size_t)l * HH * NN;
  for (int r = 0; r < 4; r++)
    tile[ty + r*8][tx] = Wl[(size_t)(k0 + ty + r*8) * NN + n0 + tx];
  __syncthreads();
  unsigned short* Wtl = Wt + (size_t)l * NN * HH;
  for (int r = 0; r < 4; r++){
    int n = n0 + ty + r*8;
    Wtl[(size_t)n * HH + k0 + tx] = f2bf(tile[tx][ty + r*8]);
  }
}

// ---------------- x fp32 -> bf16 (layer 0 only; attn_ln emits xb afterwards)
__global__ void xconv_kernel(const float* __restrict__ x, unsigned short* __restrict__ xb){
  int i = blockIdx.x * blockDim.x + threadIdx.x;
  float4 v = ((const float4*)x)[i];
  ushort4 o;
  o.x = f2bf(v.x); o.y = f2bf(v.y); o.z = f2bf(v.z); o.w = f2bf(v.w);
  *(ushort4*)(xb + (size_t)i * 4) = o;
}

// ---------------- GEMM: h[BT][NN] bf16 = xb[BT][HH] * Wt^T (Wt is [NN][HH])
// BK=64: 12 barrier-pairs x 32 MFMA (vs 24 x 16) to amortize the barrier
// drain. Unpadded [128][64] tiles; chunk swizzle: position p of row r holds
// global 16B-chunk p ^ (r&7). Read side: chunk (ks*4+q) ^ (m16&7) -- same
// zero-conflict class as R5's measured pattern.
#define BM 128
#define BN 128
#define BK 64

__global__ __launch_bounds__(256, 2) void gemm_kernel(
    const unsigned short* __restrict__ xb,
    const unsigned short* __restrict__ wt,
    unsigned short* __restrict__ hout,
    const float* __restrict__ a_srcl,
    const float* __restrict__ a_dstl,
    float* __restrict__ psrc,     // [BT][NHEADS][NBLK]
    float* __restrict__ pdst){
  __shared__ __align__(16) unsigned short xs[BM][BK];   // 16 KB
  __shared__ __align__(16) unsigned short wsd[BN][BK];  // 16 KB
  int bm = blockIdx.y * BM;
  int bn = blockIdx.x * BN;
  int tid = threadIdx.x;
  int wave = tid >> 6, lane = tid & 63;
  int m16 = lane & 15, q = lane >> 4;
  int wm = (wave >> 1) * 64, wn = (wave & 1) * 64;
  // staging: wave w stages rows [w*32, w*32+32) of both tiles in 4 segments
  // of 8 rows; lane -> (r8 = lane>>3, c8 = lane&7), fetches global chunk
  // c8 ^ r8 so stored position c8 holds global chunk c8 ^ (row&7).
  int r8 = lane >> 3, c8 = lane & 7;
  int cg = (c8 ^ r8) * 8;     // element offset of fetched chunk
  const unsigned short* ga[4]; const unsigned short* gb[4];
  unsigned short* la[4]; unsigned short* lb[4];
  #pragma unroll
  for (int s = 0; s < 4; s++){
    int row = wave * 32 + s * 8;
    ga[s] = xb + (size_t)(bm + row + r8) * HH + cg;
    gb[s] = wt + (size_t)(bn + row + r8) * HH + cg;
    la[s] = &xs[row][0];
    lb[s] = &wsd[row][0];
  }
  int rd0 = ((0 + q) ^ (m16 & 7)) * 8;   // ks=0 fragment chunk offset
  int rd1 = ((4 + q) ^ (m16 & 7)) * 8;   // ks=1
  f32x4 acc[4][4] = {};
  for (int k0 = 0; k0 < HH; k0 += BK){
    #pragma unroll
    for (int s = 0; s < 4; s++){
      gload16(ga[s] + k0, la[s]);
      gload16(gb[s] + k0, lb[s]);
    }
    __syncthreads();
    bf16x8 af[4], bfr[4];
    for (int i = 0; i < 4; i++)
      af[i] = __builtin_bit_cast(bf16x8, *(const uint4*)(&xs[wm + i*16 + m16][rd0]));
    for (int j = 0; j < 4; j++)
      bfr[j] = __builtin_bit_cast(bf16x8, *(const uint4*)(&wsd[wn + j*16 + m16][rd0]));
    for (int i = 0; i < 4; i++)
      for (int j = 0; j < 4; j++)
        acc[i][j] = __builtin_amdgcn_mfma_f32_16x16x32_bf16(af[i], bfr[j], acc[i][j], 0, 0, 0);
    for (int i = 0; i < 4; i++)
      af[i] = __builtin_bit_cast(bf16x8, *(const uint4*)(&xs[wm + i*16 + m16][rd1]));
    for (int j = 0; j < 4; j++)
      bfr[j] = __builtin_bit_cast(bf16x8, *(const uint4*)(&wsd[wn + j*16 + m16][rd1]));
    for (int i = 0; i < 4; i++)
      for (int j = 0; j < 4; j++)
        acc[i][j] = __builtin_amdgcn_mfma_f32_16x16x32_bf16(af[i], bfr[j], acc[i][j], 0, 0, 0);
    __syncthreads();
  }
  // C store (bf16)
  for (int i = 0; i < 4; i++){
    int row0 = bm + wm + i*16 + q*4;
    for (int j = 0; j < 4; j++){
      int col = bn + wn + j*16 + m16;
      unsigned short* hp = hout + (size_t)row0 * NN + col;
      hp[0]            = f2bf(acc[i][j][0]);
      hp[NN]           = f2bf(acc[i][j][1]);
      hp[2*(size_t)NN] = f2bf(acc[i][j][2]);
      hp[3*(size_t)NN] = f2bf(acc[i][j][3]);
    }
  }
  // fused asrc/adst partials: wave covers 64 cols = one (head, blk) slot
  int col0 = bn + wn;
  int head = col0 / DD;
  int blk  = (col0 % DD) >> 6;
  float wsrc[4], wdstw[4];
  for (int j = 0; j < 4; j++){
    int n = col0 + j*16 + m16;
    wsrc[j]  = a_srcl[n];
    wdstw[j] = a_dstl[n];
  }
  for (int i = 0; i < 4; i++){
    for (int reg = 0; reg < 4; reg++){
      float ss = 0.f, dd = 0.f;
      for (int j = 0; j < 4; j++){
        float v = acc[i][j][reg];
        ss += v * wsrc[j];
        dd += v * wdstw[j];
      }
      ss += __shfl_xor(ss, 1, 64); dd += __shfl_xor(dd, 1, 64);
      ss += __shfl_xor(ss, 2, 64); dd += __shfl_xor(dd, 2, 64);
      ss += __shfl_xor(ss, 4, 64); dd += __shfl_xor(dd, 4, 64);
      ss += __shfl_xor(ss, 8, 64); dd += __shfl_xor(dd, 8, 64);
      if (m16 == 0){
        int row = bm + wm + i*16 + q*4 + reg;
        size_t slot = (size_t)row * (NHEADS * NBLK) + head * NBLK + blk;
        psrc[slot] = ss;
        pdst[slot] = dd;
      }
    }
  }
}

// ---------------- reduce partials -> asrc/adst
__global__ __launch_bounds__(256) void srcred_kernel(
    const float* __restrict__ psrc, const float* __restrict__ pdst,
    float* __restrict__ asrc, float* __restrict__ adst){
  int task = blockIdx.x * 256 + threadIdx.x;   // row*NHEADS + head
  const float* ps = psrc + (size_t)task * NBLK;
  const float* pd = pdst + (size_t)task * NBLK;
  float ss = 0.f, dd = 0.f;
  for (int i = 0; i < NBLK; i++){ ss += ps[i]; dd += pd[i]; }
  asrc[task] = ss;
  adst[task] = dd;
}

// ---------------- attention + head-mean + bias + residual + layernorm
// 384 threads = 4 tokens x 96 chunks; each thread owns 8 contiguous dims ->
// all LDS reads are ds_read_b128, all global traffic float4/uint4.
__global__ __launch_bounds__(384) void attn_ln_kernel(const unsigned short* __restrict__ h,
    const float* __restrict__ asrc, const float* __restrict__ adst,
    const float* __restrict__ x_in, const float* __restrict__ bias_l,
    const float* __restrict__ gamma_l, const float* __restrict__ beta_l,
    float* __restrict__ x_out, unsigned short* __restrict__ xb_next){
  int bid = blockIdx.x;                       // 2048
  int grp = ((bid & 7) << 8) | (bid >> 3);    // XCD-contiguous groups
  int token0 = grp * ATPB;
  int t0 = token0 & (TT - 1);
  int bseq = token0 >> 11;
  int tid = threadIdx.x;
  int wave = tid >> 6, lane = tid & 63;
  __shared__ __align__(16) unsigned short hs[NROWS][NN];   // 48 KB
  __shared__ float attn_s[ATPB][NHEADS][KNB];
  __shared__ float part_s[ATPB * 96], part_q[ATPB * 96];
  __shared__ float mv_mean[ATPB], mv_rstd[ATPB];
  // stage 8 clamped rows; iteration j stages row j (384 chunks of 16B)
  #pragma unroll
  for (int j = 0; j < NROWS; j++){
    int g = t0 - 2 + j;
    g = min(max(g, 0), TT - 1);
    const unsigned short* src = h + ((size_t)(bseq * TT + g)) * NN + tid * 8;
    gload16(src, &hs[j][wave * 512]);
  }
  if (tid < ATPB * NHEADS){
    int ti = tid >> 2, head = tid & 3;
    int token = token0 + ti, t = t0 + ti;
    float sc[KNB];
    float mx = -3.0e38f;
    float ad = adst[token * NHEADS + head];
    for (int k = 0; k < KNB; k++){
      int tn = t + k - 2;
      if (tn >= 0 && tn < TT){
        float s = asrc[(token + k - 2) * NHEADS + head] + ad;
        s = s > 0.f ? s : 0.2f * s;       // leaky_relu 0.2
        sc[k] = s; mx = fmaxf(mx, s);
      } else sc[k] = -3.0e38f;
    }
    float den = 0.f;
    for (int k = 0; k < KNB; k++){
      float e = (sc[k] > -1.0e38f) ? __expf(sc[k] - mx) : 0.f;
      sc[k] = e; den += e;
    }
    float inv = 0.25f / den;              // fold 1/HEADS into attn
    for (int k = 0; k < KNB; k++) attn_s[ti][head][k] = sc[k] * inv;
  }
  __syncthreads();
  int ti = tid / 96, c = tid % 96;        // token-in-block, 8-elem chunk
  int token = token0 + ti;
  float ac[NHEADS][KNB];
  for (int hd = 0; hd < NHEADS; hd++)
    for (int k = 0; k < KNB; k++) ac[hd][k] = attn_s[ti][hd][k];
  float y8[8] = {};
  for (int hd = 0; hd < NHEADS; hd++){
    #pragma unroll
    for (int k = 0; k < KNB; k++){
      bf16x8 v = __builtin_bit_cast(bf16x8, *(const uint4*)(&hs[ti + k][hd * DD + c * 8]));
      float a = ac[hd][k];
      #pragma unroll
      for (int e = 0; e < 8; e++) y8[e] += a * (float)v[e];
    }
  }
  float xr[8], bb[8];
  { const float4* p = (const float4*)&x_in[(size_t)token * HH + c * 8];
    *(float4*)&xr[0] = p[0]; *(float4*)&xr[4] = p[1]; }
  { const float4* p = (const float4*)&bias_l[c * 8];
    *(float4*)&bb[0] = p[0]; *(float4*)&bb[4] = p[1]; }
  float s = 0.f, sq = 0.f;
  #pragma unroll
  for (int e = 0; e < 8; e++){
    float zz = y8[e] + bb[e] + xr[e];
    y8[e] = zz; s += zz; sq += zz * zz;
  }
  part_s[tid] = s; part_q[tid] = sq;
  __syncthreads();
  if (wave < ATPB){
    float vs = part_s[wave * 96 + lane];
    float vq = part_q[wave * 96 + lane];
    if (lane < 32){
      vs += part_s[wave * 96 + 64 + lane];
      vq += part_q[wave * 96 + 64 + lane];
    }
    for (int off = 32; off > 0; off >>= 1){
      vs += __shfl_xor(vs, off, 64);
      vq += __shfl_xor(vq, off, 64);
    }
    if (lane == 0){
      float mean = vs * (1.f / HH);
      float var = vq * (1.f / HH) - mean * mean;
      mv_mean[wave] = mean;
      mv_rstd[wave] = rsqrtf(var + 1e-5f);
    }
  }
  __syncthreads();
  float mean = mv_mean[ti], rstd = mv_rstd[ti];
  float gr[8], br[8];
  { const float4* p = (const float4*)&gamma_l[c * 8];
    *(float4*)&gr[0] = p[0]; *(float4*)&gr[4] = p[1]; }
  { const float4* p = (const float4*)&beta_l[c * 8];
    *(float4*)&br[0] = p[0]; *(float4*)&br[4] = p[1]; }
  float o[8];
  unsigned short o16[8];
  #pragma unroll
  for (int e = 0; e < 8; e++){
    o[e] = (y8[e] - mean) * rstd * gr[e] + br[e];
    o16[e] = f2bf(o[e]);
  }
  float* xo = &x_out[(size_t)token * HH + c * 8];
  *(float4*)&xo[0] = *(float4*)&o[0];
  *(float4*)&xo[4] = *(float4*)&o[4];
  *(uint4*)(&xb_next[(size_t)token * HH + c * 8]) = *(uint4*)&o16[0];
}

extern "C" void kernel_launch(void* const* d_in, const int* in_sizes, int n_in,
                              void* d_out, int out_size, void* d_ws, size_t ws_size,
                              hipStream_t stream) {
  const float* x     = (const float*)d_in[0];
  const float* W     = (const float*)d_in[1];
  const float* a_src = (const float*)d_in[2];
  const float* a_dst = (const float*)d_in[3];
  const float* bias  = (const float*)d_in[4];
  const float* gamma = (const float*)d_in[5];
  const float* beta  = (const float*)d_in[6];
  float* out = (float*)d_out;

  char* ws = (char*)d_ws;
  size_t off = 0;
  auto alloc = [&](size_t bytes)->char*{
    char* p = ws + off;
    off = (off + bytes + 255) & ~(size_t)255;
    return p;
  };
  unsigned short* wt   = (unsigned short*)alloc((size_t)LL * NN * HH * 2);
  unsigned short* xb   = (unsigned short*)alloc((size_t)BT * HH * 2);
  unsigned short* hbuf = (unsigned short*)alloc((size_t)BT * NN * 2);
  float* psrc  = (float*)alloc((size_t)BT * NHEADS * NBLK * 4);
  float* pdst  = (float*)alloc((size_t)BT * NHEADS * NBLK * 4);
  float* asrcb = (float*)alloc((size_t)BT * NHEADS * 4);
  float* adstb = (float*)alloc((size_t)BT * NHEADS * 4);

  wt_kernel<<<dim3(NN/32, HH/32, LL), dim3(32, 8), 0, stream>>>(W, wt);
  xconv_kernel<<<(BT * HH / 4) / 256, 256, 0, stream>>>(x, xb);

  for (int l = 0; l < LL; l++){
    const float* xin = (l == 0) ? x : out;
    gemm_kernel<<<dim3(NN / BN, BT / BM), 256, 0, stream>>>(
        xb, wt + (size_t)l * NN * HH, hbuf,
        a_src + (size_t)l * NHEADS * DD, a_dst + (size_t)l * NHEADS * DD,
        psrc, pdst);
    srcred_kernel<<<BT * NHEADS / 256, 256, 0, stream>>>(psrc, pdst, asrcb, adstb);
    attn_ln_kernel<<<BT / ATPB, 384, 0, stream>>>(hbuf, asrcb, adstb, xin,
        bias + (size_t)l * DD, gamma + (size_t)l * HH, beta + (size_t)l * HH,
        out, xb);
  }
}